// Round 1
// baseline (300.448 us; speedup 1.0000x reference)
//
#include <hip/hip_runtime.h>
#include <math.h>

// OrbitalCofactorAntiequivarianceLayer fused kernel for MI355X (gfx950).
// B=4096, NSPIN=2, NPS=16, D=256, NION=8, DIM=3.
// 2048 blocks x 256 threads; blk<1024 -> s=0, else s=1; each of the 4 waves
// owns pair b = (blk&1023)*4 + wave.
//
// R6 -> R7: kernel was latency-bound (VALUBusy 37%, Occupancy 23%, HBM 11%).
// (1) LDS 35840 -> 19456 B: x staged in four 16x64 quarters per wave (4 KB),
//     2-buffer software pipeline, same XOR swizzle / identical FP order.
//     With __launch_bounds__(256,7): 7 blocks/CU (was 4).
// (2) Phase D runs per-wave on the wave's OWN M (replicated across its four
//     16-lane groups; output from group 0) -> trailing __syncthreads removed,
//     waves retire independently, 4 LU chains/block run on 4 SIMDs.
// (3) VGPR diet: staging regs halved (stA/stB = 4 float4 each), piv[16]
//     packed into two u32.

__global__ __launch_bounds__(256, 7)
void cof_fused(const float* __restrict__ eq,    // (B,32,256)
               const float* __restrict__ rei,   // (B,32,8,3)
               const float* __restrict__ Wm,    // (2,256,16)
               const float* __restrict__ bb,    // (2,16)
               const float* __restrict__ edim,  // (2,8,16,3,3)
               const float* __restrict__ eion,  // (2,8,16)
               float* __restrict__ out)         // (B,2,16)
{
  __shared__ __align__(16) float Gl[8 * 6 * 16];   // Gram coeffs, SoA [i][c6][o]
  __shared__ __align__(16) float Xl[4 * 1024];     // per-wave x quarter (16x64),
                                                   // later overlaid by M (16 x stride 20)

  const int tid   = threadIdx.x;
  const int lane  = tid & 63;
  const int wv    = tid >> 6;
  const int blk   = blockIdx.x;
  const int sp    = blk >> 10;           // spin index
  const int bbase = (blk & 1023) * 4;

  // ---- Gram precompute: G = A^T A per (i,o), cross terms pre-doubled ----
  if (tid < 128) {
    const int i = tid >> 4, o = tid & 15;
    const float* A = edim + (((size_t)sp * 8 + i) * 16 + o) * 9;
    const float a0=A[0],a1=A[1],a2=A[2],a3=A[3],a4=A[4],a5=A[5],a6=A[6],a7=A[7],a8=A[8];
    float* Gp = Gl + i * 96 + o;
    Gp[0]  = a0*a0 + a3*a3 + a6*a6;
    Gp[16] = a1*a1 + a4*a4 + a7*a7;
    Gp[32] = a2*a2 + a5*a5 + a8*a8;
    Gp[48] = 2.f*(a0*a1 + a3*a4 + a6*a7);
    Gp[64] = 2.f*(a0*a2 + a3*a5 + a6*a8);
    Gp[80] = 2.f*(a1*a2 + a4*a5 + a7*a8);
  }
  __syncthreads();

  const int bidx = bbase + wv;
  const int cch  = lane >> 4;        // K-chunk within a 16-float group
  const int nb   = (lane >> 2) & 3;  // row-tile
  const int ob   = lane & 3;         // col-tile

  const float* xb = eq + ((size_t)bidx * 32 + sp * 16) * 256;
  const float* wb = Wm + (size_t)sp * 4096;
  float* xw = Xl + wv * 1024;

  const int srow = lane >> 4;        // staging row base 0..3
  const int schk = lane & 15;        // staging float4-chunk within 64-float row

  float acc[4][4] = {{0.f,0.f,0.f,0.f},{0.f,0.f,0.f,0.f},
                     {0.f,0.f,0.f,0.f},{0.f,0.f,0.f,0.f}};

  // ---- Phase A: y = xs @ W. Stage x in 16x64 quarters, coalesced,
  // XOR-swizzled, 2-buffer software pipeline. Same d-accumulation order
  // as the 128-wide-half version (q = qq*4+g), so results are bit-identical.
  float4 stA[4], stB[4];

#define LOADQ(dst, qq)                                                        \
  _Pragma("unroll")                                                           \
  for (int t = 0; t < 4; ++t)                                                 \
    dst[t] = *(const float4*)(xb + (4 * t + srow) * 256 + (qq) * 64 + schk * 4);

#define WRITEQ(src)                                                           \
  _Pragma("unroll")                                                           \
  for (int t = 0; t < 4; ++t) {                                               \
    const int row_ = 4 * t + srow;                                            \
    *(float4*)(xw + row_ * 64 + ((schk ^ (row_ & 7)) * 4)) = src[t];          \
  }

#define COMPQ(qq)                                                             \
  _Pragma("unroll")                                                           \
  for (int g = 0; g < 4; ++g) {                                               \
    const int dg = (qq) * 64 + g * 16 + cch * 4;                              \
    float xr[4][4], wr4[4][4];                                                \
    _Pragma("unroll")                                                         \
    for (int r = 0; r < 4; ++r) {                                             \
      const int n_ = 4 * nb + r;                                              \
      float4 t = *(const float4*)(xw + n_ * 64 +                              \
                                  (((g * 4 + cch) ^ (n_ & 7)) * 4));          \
      xr[r][0]=t.x; xr[r][1]=t.y; xr[r][2]=t.z; xr[r][3]=t.w;                 \
    }                                                                         \
    _Pragma("unroll")                                                         \
    for (int j = 0; j < 4; ++j) {                                             \
      float4 t = *(const float4*)(wb + (dg + j) * 16 + 4 * ob);               \
      wr4[j][0]=t.x; wr4[j][1]=t.y; wr4[j][2]=t.z; wr4[j][3]=t.w;             \
    }                                                                         \
    _Pragma("unroll")                                                         \
    for (int r = 0; r < 4; ++r)                                               \
      _Pragma("unroll")                                                       \
      for (int j = 0; j < 4; ++j)                                             \
        _Pragma("unroll")                                                     \
        for (int c2 = 0; c2 < 4; ++c2)                                        \
          acc[r][c2] = fmaf(xr[r][j], wr4[j][c2], acc[r][c2]);                \
  }

  LOADQ(stA, 0)
  WRITEQ(stA)
  LOADQ(stB, 1)
  COMPQ(0)            // reads quarter 0 (in-order LDS: precedes overwrite)
  WRITEQ(stB)
  LOADQ(stA, 2)
  COMPQ(1)
  WRITEQ(stA)
  LOADQ(stB, 3)
  COMPQ(2)
  WRITEQ(stB)
  COMPQ(3)

#undef LOADQ
#undef WRITEQ
#undef COMPQ

  // reduce over K-chunks (lane bits 4-5)
  #pragma unroll
  for (int r = 0; r < 4; ++r)
    #pragma unroll
    for (int c2 = 0; c2 < 4; ++c2) {
      float v = acc[r][c2];
      v += __shfl_xor(v, 16);
      v += __shfl_xor(v, 32);
      acc[r][c2] = v;
    }

  // M overlays this wave's x buffer (x fully consumed by this wave).
  float* Mw = xw;   // 16 rows, stride 20 floats
  {
    float4 bv = *(const float4*)(bb + sp * 16 + 4 * ob);
    if (lane < 16) {
      #pragma unroll
      for (int r = 0; r < 4; ++r) {
        float4 v = make_float4(acc[r][0] + bv.x, acc[r][1] + bv.y,
                               acc[r][2] + bv.z, acc[r][3] + bv.w);
        *(float4*)(Mw + (4 * nb + r) * 20 + 4 * ob) = v;
      }
    }
  }

  // ---- Phase C: envelope; M = y * env (in place, own-wave region) ----
  {
    const int n = lane >> 2;           // row 0..15, cols 4*ob..4*ob+3
    const float* rp = rei + ((size_t)bidx * 32 + sp * 16 + n) * 24;
    float rv[24];
    #pragma unroll
    for (int t4 = 0; t4 < 6; ++t4) {
      float4 t = *(const float4*)(rp + t4 * 4);
      rv[t4*4+0]=t.x; rv[t4*4+1]=t.y; rv[t4*4+2]=t.z; rv[t4*4+3]=t.w;
    }
    float4 env = make_float4(0.f, 0.f, 0.f, 0.f);
    #pragma unroll
    for (int i = 0; i < 8; ++i) {
      const float r0 = rv[i*3], r1 = rv[i*3+1], r2 = rv[i*3+2];
      const float rr0 = r0*r0, rr1 = r1*r1, rr2 = r2*r2;
      const float rr3 = r0*r1, rr4 = r0*r2, rr5 = r1*r2;
      const float* Gp = Gl + i * 96 + 4 * ob;
      const float4 q00 = *(const float4*)(Gp);
      const float4 q11 = *(const float4*)(Gp + 16);
      const float4 q22 = *(const float4*)(Gp + 32);
      const float4 q01 = *(const float4*)(Gp + 48);
      const float4 q02 = *(const float4*)(Gp + 64);
      const float4 q12 = *(const float4*)(Gp + 80);
      const float4 io  = *(const float4*)(eion + ((size_t)sp * 8 + i) * 16 + 4 * ob);
#define ENVC(c) { float n2 = q00.c*rr0 + q11.c*rr1 + q22.c*rr2 \
                           + q01.c*rr3 + q02.c*rr4 + q12.c*rr5; \
                  n2 = fmaxf(n2, 0.f); \
                  env.c += __expf(-sqrtf(n2)) * io.c; }
      ENVC(x) ENVC(y) ENVC(z) ENVC(w)
#undef ENVC
    }
    float* mp = Mw + n * 20 + 4 * ob;
    float4 y = *(const float4*)mp;
    *(float4*)mp = make_float4(y.x * env.x, y.y * env.y, y.z * env.z, y.w * env.w);
  }

  // ---- Phase D: cofactor, per-wave on own M (no barrier needed: same wave
  // wrote M). The 16-lane LU is replicated across the wave's four 16-lane
  // groups (redundant lanes are free); group 0 stores the result.
  // A = M^T, fp32 LU with virtual partial pivoting; cof[i] = M[i,0]*det*x[i],
  // x = A^{-1} e0 (= row 0 of M^{-1}).
  {
    const int r  = lane & 15;        // my row of A (= column r of M)
    const int gb = lane & 48;        // group base for shuffles
    float a[16];
    #pragma unroll
    for (int c = 0; c < 16; ++c) a[c] = Mw[c * 20 + r];

    float det = 1.0f;
    int sign = 0;
    unsigned retired = 0;
    unsigned pp0 = 0, pp1 = 0;       // packed pivot indices, 4 bits each
    int srr = 0;
    float accf = (r == 0) ? 1.0f : 0.0f;  // forward rhs (P e0 component)
    float acc2 = 0.0f;                    // z captured at my retirement

    #pragma unroll
    for (int k = 0; k < 16; ++k) {
      const bool act = ((retired >> r) & 1u) == 0u;
      const float av = act ? fabsf(a[k]) : 0.0f;
      unsigned pk = (__float_as_uint(av) & 0xFFFFFFF0u) | (unsigned)r;
      #pragma unroll
      for (int m = 1; m <= 8; m <<= 1) {
        unsigned o2 = __shfl_xor(pk, m);
        pk = (pk > o2) ? pk : o2;
      }
      const int p = (int)(pk & 15u);
      if (k < 8) pp0 |= (unsigned)p << (4 * k);
      else       pp1 |= (unsigned)p << (4 * (k - 8));
      float pv = __shfl(a[k], gb | p);
      if (fabsf(pv) < 1e-30f) pv = (pv < 0.0f) ? -1e-30f : 1e-30f;
      det *= pv;
      retired |= (1u << p);
      sign ^= (int)(__popc((~retired) & ((1u << p) - 1u)) & 1u);
      if (r == p) srr = k;
      const bool upd = act && (r != p);
      float m2 = 0.0f;
      if (upd) { m2 = a[k] / pv; a[k] = m2; }
      #pragma unroll
      for (int c = k + 1; c < 16; ++c) {
        float bcv = __shfl(a[c], gb | p);
        if (upd) a[c] = fmaf(-m2, bcv, a[c]);
      }
      // fused forward solve L z = P e0
      float zk = __shfl(accf, gb | p);
      if (r == p) acc2 = zk;
      if (upd) accf = fmaf(-m2, zk, accf);
    }
    if (sign) det = -det;

    // backward solve U x = z
    float myx = 0.0f;
    #pragma unroll
    for (int j = 15; j >= 0; --j) {
      float t = acc2 / a[j];                   // valid on pivot lane of step j
      const int pj = (int)(((j >= 8) ? (pp1 >> (4 * (j - 8)))
                                     : (pp0 >> (4 * j))) & 15u);
      float xj = __shfl(t, gb | pj);
      if (srr < j) acc2 = fmaf(-a[j], xj, acc2);
      if (r == j) myx = xj;
    }

    const float mi0 = Mw[r * 20];              // M[r][0]
    const float cof = mi0 * det * myx;
    if (lane < 16)
      out[((size_t)bidx * 2 + sp) * 16 + r] = cof;
  }
}

extern "C" void kernel_launch(void* const* d_in, const int* in_sizes, int n_in,
                              void* d_out, int out_size, void* d_ws, size_t ws_size,
                              hipStream_t stream) {
  (void)in_sizes; (void)n_in; (void)out_size; (void)d_ws; (void)ws_size;
  const float* eq   = (const float*)d_in[0];
  const float* rei  = (const float*)d_in[1];
  const float* Wm   = (const float*)d_in[2];
  const float* bb   = (const float*)d_in[3];
  const float* edim = (const float*)d_in[4];
  const float* eion = (const float*)d_in[5];
  float* out = (float*)d_out;
  hipLaunchKernelGGL(cof_fused, dim3(2048), dim3(256), 0, stream,
                     eq, rei, Wm, bb, edim, eion, out);
}

// Round 2
// 229.719 us; speedup vs baseline: 1.3079x; 1.3079x over previous
//
#include <hip/hip_runtime.h>
#include <math.h>

// OrbitalCofactorAntiequivarianceLayer fused kernel for MI355X (gfx950).
// B=4096, NSPIN=2, NPS=16, D=256, NION=8, DIM=3.
// 2048 blocks x 256 threads; blk<1024 -> s=0, else s=1; each of the 4 waves
// owns pair b = (blk&1023)*4 + wave.
//
// R7 -> R8: R7's __launch_bounds__(256,7) capped VGPR at 256/7=36 (min-waves
// is budgeted against the 256 addressable VGPRs, NOT the 512 unified file)
// -> ~53KB/block scratch spills (WRITE_SIZE 0.5MB -> 108MB), dur 86 -> 160us.
// Fix: no min-waves. Natural allocation (~72 VGPR) already gives
// floor(512/72)=7 waves/SIMD on the unified file; LDS 19456B allows 8
// blocks/CU, so occupancy is ~7 blocks/CU without any forced cap.
// Kept from R7 (verified correct, absmax 2.8e-14):
// (1) LDS 35840 -> 19456 B: x staged in four 16x64 quarters per wave (4 KB),
//     2-buffer software pipeline, same XOR swizzle / identical FP order.
// (2) Phase D per-wave on the wave's OWN M (replicated across its four
//     16-lane groups; output from group 0) -> no trailing __syncthreads,
//     waves retire independently, 4 LU chains/block run on 4 SIMDs.
// (3) piv[16] packed into two u32.

__global__ __launch_bounds__(256)
void cof_fused(const float* __restrict__ eq,    // (B,32,256)
               const float* __restrict__ rei,   // (B,32,8,3)
               const float* __restrict__ Wm,    // (2,256,16)
               const float* __restrict__ bb,    // (2,16)
               const float* __restrict__ edim,  // (2,8,16,3,3)
               const float* __restrict__ eion,  // (2,8,16)
               float* __restrict__ out)         // (B,2,16)
{
  __shared__ __align__(16) float Gl[8 * 6 * 16];   // Gram coeffs, SoA [i][c6][o]
  __shared__ __align__(16) float Xl[4 * 1024];     // per-wave x quarter (16x64),
                                                   // later overlaid by M (16 x stride 20)

  const int tid   = threadIdx.x;
  const int lane  = tid & 63;
  const int wv    = tid >> 6;
  const int blk   = blockIdx.x;
  const int sp    = blk >> 10;           // spin index
  const int bbase = (blk & 1023) * 4;

  // ---- Gram precompute: G = A^T A per (i,o), cross terms pre-doubled ----
  if (tid < 128) {
    const int i = tid >> 4, o = tid & 15;
    const float* A = edim + (((size_t)sp * 8 + i) * 16 + o) * 9;
    const float a0=A[0],a1=A[1],a2=A[2],a3=A[3],a4=A[4],a5=A[5],a6=A[6],a7=A[7],a8=A[8];
    float* Gp = Gl + i * 96 + o;
    Gp[0]  = a0*a0 + a3*a3 + a6*a6;
    Gp[16] = a1*a1 + a4*a4 + a7*a7;
    Gp[32] = a2*a2 + a5*a5 + a8*a8;
    Gp[48] = 2.f*(a0*a1 + a3*a4 + a6*a7);
    Gp[64] = 2.f*(a0*a2 + a3*a5 + a6*a8);
    Gp[80] = 2.f*(a1*a2 + a4*a5 + a7*a8);
  }
  __syncthreads();

  const int bidx = bbase + wv;
  const int cch  = lane >> 4;        // K-chunk within a 16-float group
  const int nb   = (lane >> 2) & 3;  // row-tile
  const int ob   = lane & 3;         // col-tile

  const float* xb = eq + ((size_t)bidx * 32 + sp * 16) * 256;
  const float* wb = Wm + (size_t)sp * 4096;
  float* xw = Xl + wv * 1024;

  const int srow = lane >> 4;        // staging row base 0..3
  const int schk = lane & 15;        // staging float4-chunk within 64-float row

  float acc[4][4] = {{0.f,0.f,0.f,0.f},{0.f,0.f,0.f,0.f},
                     {0.f,0.f,0.f,0.f},{0.f,0.f,0.f,0.f}};

  // ---- Phase A: y = xs @ W. Stage x in 16x64 quarters, coalesced,
  // XOR-swizzled, 2-buffer software pipeline. Same d-accumulation order
  // as the 128-wide-half version (q = qq*4+g), so results are bit-identical.
  float4 stA[4], stB[4];

#define LOADQ(dst, qq)                                                        \
  _Pragma("unroll")                                                           \
  for (int t = 0; t < 4; ++t)                                                 \
    dst[t] = *(const float4*)(xb + (4 * t + srow) * 256 + (qq) * 64 + schk * 4);

#define WRITEQ(src)                                                           \
  _Pragma("unroll")                                                           \
  for (int t = 0; t < 4; ++t) {                                               \
    const int row_ = 4 * t + srow;                                            \
    *(float4*)(xw + row_ * 64 + ((schk ^ (row_ & 7)) * 4)) = src[t];          \
  }

#define COMPQ(qq)                                                             \
  _Pragma("unroll")                                                           \
  for (int g = 0; g < 4; ++g) {                                               \
    const int dg = (qq) * 64 + g * 16 + cch * 4;                              \
    float xr[4][4], wr4[4][4];                                                \
    _Pragma("unroll")                                                         \
    for (int r = 0; r < 4; ++r) {                                             \
      const int n_ = 4 * nb + r;                                              \
      float4 t = *(const float4*)(xw + n_ * 64 +                              \
                                  (((g * 4 + cch) ^ (n_ & 7)) * 4));          \
      xr[r][0]=t.x; xr[r][1]=t.y; xr[r][2]=t.z; xr[r][3]=t.w;                 \
    }                                                                         \
    _Pragma("unroll")                                                         \
    for (int j = 0; j < 4; ++j) {                                             \
      float4 t = *(const float4*)(wb + (dg + j) * 16 + 4 * ob);               \
      wr4[j][0]=t.x; wr4[j][1]=t.y; wr4[j][2]=t.z; wr4[j][3]=t.w;             \
    }                                                                         \
    _Pragma("unroll")                                                         \
    for (int r = 0; r < 4; ++r)                                               \
      _Pragma("unroll")                                                       \
      for (int j = 0; j < 4; ++j)                                             \
        _Pragma("unroll")                                                     \
        for (int c2 = 0; c2 < 4; ++c2)                                        \
          acc[r][c2] = fmaf(xr[r][j], wr4[j][c2], acc[r][c2]);                \
  }

  LOADQ(stA, 0)
  WRITEQ(stA)
  LOADQ(stB, 1)
  COMPQ(0)            // reads quarter 0 (in-order LDS: precedes overwrite)
  WRITEQ(stB)
  LOADQ(stA, 2)
  COMPQ(1)
  WRITEQ(stA)
  LOADQ(stB, 3)
  COMPQ(2)
  WRITEQ(stB)
  COMPQ(3)

#undef LOADQ
#undef WRITEQ
#undef COMPQ

  // reduce over K-chunks (lane bits 4-5)
  #pragma unroll
  for (int r = 0; r < 4; ++r)
    #pragma unroll
    for (int c2 = 0; c2 < 4; ++c2) {
      float v = acc[r][c2];
      v += __shfl_xor(v, 16);
      v += __shfl_xor(v, 32);
      acc[r][c2] = v;
    }

  // M overlays this wave's x buffer (x fully consumed by this wave).
  float* Mw = xw;   // 16 rows, stride 20 floats
  {
    float4 bv = *(const float4*)(bb + sp * 16 + 4 * ob);
    if (lane < 16) {
      #pragma unroll
      for (int r = 0; r < 4; ++r) {
        float4 v = make_float4(acc[r][0] + bv.x, acc[r][1] + bv.y,
                               acc[r][2] + bv.z, acc[r][3] + bv.w);
        *(float4*)(Mw + (4 * nb + r) * 20 + 4 * ob) = v;
      }
    }
  }

  // ---- Phase C: envelope; M = y * env (in place, own-wave region) ----
  {
    const int n = lane >> 2;           // row 0..15, cols 4*ob..4*ob+3
    const float* rp = rei + ((size_t)bidx * 32 + sp * 16 + n) * 24;
    float rv[24];
    #pragma unroll
    for (int t4 = 0; t4 < 6; ++t4) {
      float4 t = *(const float4*)(rp + t4 * 4);
      rv[t4*4+0]=t.x; rv[t4*4+1]=t.y; rv[t4*4+2]=t.z; rv[t4*4+3]=t.w;
    }
    float4 env = make_float4(0.f, 0.f, 0.f, 0.f);
    #pragma unroll
    for (int i = 0; i < 8; ++i) {
      const float r0 = rv[i*3], r1 = rv[i*3+1], r2 = rv[i*3+2];
      const float rr0 = r0*r0, rr1 = r1*r1, rr2 = r2*r2;
      const float rr3 = r0*r1, rr4 = r0*r2, rr5 = r1*r2;
      const float* Gp = Gl + i * 96 + 4 * ob;
      const float4 q00 = *(const float4*)(Gp);
      const float4 q11 = *(const float4*)(Gp + 16);
      const float4 q22 = *(const float4*)(Gp + 32);
      const float4 q01 = *(const float4*)(Gp + 48);
      const float4 q02 = *(const float4*)(Gp + 64);
      const float4 q12 = *(const float4*)(Gp + 80);
      const float4 io  = *(const float4*)(eion + ((size_t)sp * 8 + i) * 16 + 4 * ob);
#define ENVC(c) { float n2 = q00.c*rr0 + q11.c*rr1 + q22.c*rr2 \
                           + q01.c*rr3 + q02.c*rr4 + q12.c*rr5; \
                  n2 = fmaxf(n2, 0.f); \
                  env.c += __expf(-sqrtf(n2)) * io.c; }
      ENVC(x) ENVC(y) ENVC(z) ENVC(w)
#undef ENVC
    }
    float* mp = Mw + n * 20 + 4 * ob;
    float4 y = *(const float4*)mp;
    *(float4*)mp = make_float4(y.x * env.x, y.y * env.y, y.z * env.z, y.w * env.w);
  }

  // ---- Phase D: cofactor, per-wave on own M (no barrier needed: same wave
  // wrote M). The 16-lane LU is replicated across the wave's four 16-lane
  // groups (redundant lanes are free); group 0 stores the result.
  // A = M^T, fp32 LU with virtual partial pivoting; cof[i] = M[i,0]*det*x[i],
  // x = A^{-1} e0 (= row 0 of M^{-1}).
  {
    const int r  = lane & 15;        // my row of A (= column r of M)
    const int gb = lane & 48;        // group base for shuffles
    float a[16];
    #pragma unroll
    for (int c = 0; c < 16; ++c) a[c] = Mw[c * 20 + r];

    float det = 1.0f;
    int sign = 0;
    unsigned retired = 0;
    unsigned pp0 = 0, pp1 = 0;       // packed pivot indices, 4 bits each
    int srr = 0;
    float accf = (r == 0) ? 1.0f : 0.0f;  // forward rhs (P e0 component)
    float acc2 = 0.0f;                    // z captured at my retirement

    #pragma unroll
    for (int k = 0; k < 16; ++k) {
      const bool act = ((retired >> r) & 1u) == 0u;
      const float av = act ? fabsf(a[k]) : 0.0f;
      unsigned pk = (__float_as_uint(av) & 0xFFFFFFF0u) | (unsigned)r;
      #pragma unroll
      for (int m = 1; m <= 8; m <<= 1) {
        unsigned o2 = __shfl_xor(pk, m);
        pk = (pk > o2) ? pk : o2;
      }
      const int p = (int)(pk & 15u);
      if (k < 8) pp0 |= (unsigned)p << (4 * k);
      else       pp1 |= (unsigned)p << (4 * (k - 8));
      float pv = __shfl(a[k], gb | p);
      if (fabsf(pv) < 1e-30f) pv = (pv < 0.0f) ? -1e-30f : 1e-30f;
      det *= pv;
      retired |= (1u << p);
      sign ^= (int)(__popc((~retired) & ((1u << p) - 1u)) & 1u);
      if (r == p) srr = k;
      const bool upd = act && (r != p);
      float m2 = 0.0f;
      if (upd) { m2 = a[k] / pv; a[k] = m2; }
      #pragma unroll
      for (int c = k + 1; c < 16; ++c) {
        float bcv = __shfl(a[c], gb | p);
        if (upd) a[c] = fmaf(-m2, bcv, a[c]);
      }
      // fused forward solve L z = P e0
      float zk = __shfl(accf, gb | p);
      if (r == p) acc2 = zk;
      if (upd) accf = fmaf(-m2, zk, accf);
    }
    if (sign) det = -det;

    // backward solve U x = z
    float myx = 0.0f;
    #pragma unroll
    for (int j = 15; j >= 0; --j) {
      float t = acc2 / a[j];                   // valid on pivot lane of step j
      const int pj = (int)(((j >= 8) ? (pp1 >> (4 * (j - 8)))
                                     : (pp0 >> (4 * j))) & 15u);
      float xj = __shfl(t, gb | pj);
      if (srr < j) acc2 = fmaf(-a[j], xj, acc2);
      if (r == j) myx = xj;
    }

    const float mi0 = Mw[r * 20];              // M[r][0]
    const float cof = mi0 * det * myx;
    if (lane < 16)
      out[((size_t)bidx * 2 + sp) * 16 + r] = cof;
  }
}

extern "C" void kernel_launch(void* const* d_in, const int* in_sizes, int n_in,
                              void* d_out, int out_size, void* d_ws, size_t ws_size,
                              hipStream_t stream) {
  (void)in_sizes; (void)n_in; (void)out_size; (void)d_ws; (void)ws_size;
  const float* eq   = (const float*)d_in[0];
  const float* rei  = (const float*)d_in[1];
  const float* Wm   = (const float*)d_in[2];
  const float* bb   = (const float*)d_in[3];
  const float* edim = (const float*)d_in[4];
  const float* eion = (const float*)d_in[5];
  float* out = (float*)d_out;
  hipLaunchKernelGGL(cof_fused, dim3(2048), dim3(256), 0, stream,
                     eq, rei, Wm, bb, edim, eion, out);
}